// Round 1
// baseline (217.632 us; speedup 1.0000x reference)
//
#include <hip/hip_runtime.h>

// SSIM loss, fused: separable 11x11 Gaussian over 5 fields (x, y, x^2, y^2, xy),
// SSIM map + mean fused in one tiled kernel + tiny finish kernel.
//
// Layout per block: 32x32 output tile of one (n,c) image plane.
//   phase 1: stage 42x42 (halo=5) x,y tiles in LDS (zero-padded OOB)
//   phase 2: horizontal 11-tap conv -> 5 fields in LDS (42 rows x 32 cols)
//            each thread computes 4 consecutive cols (sliding-window share)
//   phase 3: vertical 11-tap conv in registers (4 consecutive rows/thread)
//            + SSIM pointwise + block reduction -> partial[block]
//   finish:  1 block reduces 12288 partials -> out[0] = 1 - mean

namespace {
constexpr int IMG  = 512;
constexpr int NCH  = 48;              // 16 images * 3 channels
constexpr int TS   = 32;              // output tile edge
constexpr int HALO = 5;
constexpr int ITS  = TS + 2 * HALO;   // 42 = staged input tile edge
constexpr int LSTR = ITS + 1;         // 43 = padded LDS stride (odd -> no 4-way conflicts)
constexpr int TPR  = IMG / TS;        // 16 tiles per row
constexpr int NBLK = TPR * TPR * NCH; // 12288 blocks
}

__global__ __launch_bounds__(256) void ssim_tile_kernel(
    const float* __restrict__ pred, const float* __restrict__ tgt,
    float* __restrict__ partial)
{
    // 1D Gaussian, sigma=1.5, k=11, normalized (double-precision derived)
    constexpr float W[11] = {
        0.00102838f, 0.00759876f, 0.03600077f, 0.10936069f, 0.21300554f,
        0.26601172f,
        0.21300554f, 0.10936069f, 0.03600077f, 0.00759876f, 0.00102838f };

    __shared__ float sx[ITS][LSTR];       // 7.2 KB
    __shared__ float sy[ITS][LSTR];       // 7.2 KB
    __shared__ float hf[5][ITS][TS];      // 26.9 KB: horizontal conv of 5 fields
    __shared__ float wred[4];

    const int t    = threadIdx.x;
    const int bid  = blockIdx.x;
    const int img  = bid >> 8;            // / 256 tiles per plane
    const int tile = bid & 255;
    const int tx   = (tile & (TPR - 1)) * TS;
    const int ty   = (tile / TPR) * TS;

    const float* __restrict__ p = pred + (size_t)img * (IMG * IMG);
    const float* __restrict__ q = tgt  + (size_t)img * (IMG * IMG);

    // ---------------- phase 1: stage x,y tiles with zero halo ----------------
    for (int l = t; l < ITS * ITS; l += 256) {
        int r  = l / ITS;
        int c  = l - r * ITS;
        int gy = ty + r - HALO;
        int gx = tx + c - HALO;
        bool ok = ((unsigned)gy < (unsigned)IMG) && ((unsigned)gx < (unsigned)IMG);
        float xv = 0.f, yv = 0.f;
        if (ok) {
            int gi = gy * IMG + gx;
            xv = p[gi];
            yv = q[gi];
        }
        sx[r][c] = xv;
        sy[r][c] = yv;
    }
    __syncthreads();

    // ------- phase 2: horizontal conv, 42 rows x 8 col-groups of 4 ----------
    for (int item = t; item < ITS * (TS / 4); item += 256) {
        int row = item >> 3;
        int c0  = (item & 7) * 4;
        float a0[4] = {0,0,0,0}, a1[4] = {0,0,0,0}, a2[4] = {0,0,0,0},
              a3[4] = {0,0,0,0}, a4[4] = {0,0,0,0};
        #pragma unroll
        for (int i = 0; i < 14; ++i) {
            float xv = sx[row][c0 + i];
            float yv = sy[row][c0 + i];
            float xx = xv * xv, yy = yv * yv, xy = xv * yv;
            #pragma unroll
            for (int j = 0; j < 4; ++j) {
                int k = i - j;
                if (k >= 0 && k < 11) {
                    float w = W[k];
                    a0[j] += w * xv; a1[j] += w * yv;
                    a2[j] += w * xx; a3[j] += w * yy; a4[j] += w * xy;
                }
            }
        }
        #pragma unroll
        for (int j = 0; j < 4; ++j) {
            hf[0][row][c0 + j] = a0[j];
            hf[1][row][c0 + j] = a1[j];
            hf[2][row][c0 + j] = a2[j];
            hf[3][row][c0 + j] = a3[j];
            hf[4][row][c0 + j] = a4[j];
        }
    }
    __syncthreads();

    // ------- phase 3: vertical conv (4 rows/thread) + SSIM + reduce ---------
    const int c  = t & 31;
    const int r0 = (t >> 5) * 4;
    float b0[4] = {0,0,0,0}, b1[4] = {0,0,0,0}, b2[4] = {0,0,0,0},
          b3[4] = {0,0,0,0}, b4[4] = {0,0,0,0};
    #pragma unroll
    for (int i = 0; i < 14; ++i) {
        float v0 = hf[0][r0 + i][c];
        float v1 = hf[1][r0 + i][c];
        float v2 = hf[2][r0 + i][c];
        float v3 = hf[3][r0 + i][c];
        float v4 = hf[4][r0 + i][c];
        #pragma unroll
        for (int j = 0; j < 4; ++j) {
            int k = i - j;
            if (k >= 0 && k < 11) {
                float w = W[k];
                b0[j] += w * v0; b1[j] += w * v1; b2[j] += w * v2;
                b3[j] += w * v3; b4[j] += w * v4;
            }
        }
    }

    constexpr float C1 = 1e-4f;   // 0.01^2
    constexpr float C2 = 9e-4f;   // 0.03^2
    float lsum = 0.f;
    #pragma unroll
    for (int j = 0; j < 4; ++j) {
        float mx  = b0[j], my = b1[j];
        float mxs = mx * mx, mys = my * my, mxy = mx * my;
        float sgx  = b2[j] - mxs;
        float sgy  = b3[j] - mys;
        float sgxy = b4[j] - mxy;
        float num = (2.f * mxy + C1) * (2.f * sgxy + C2);
        float den = (mxs + mys + C1) * (sgx + sgy + C2);
        lsum += num / den;
    }

    #pragma unroll
    for (int off = 32; off > 0; off >>= 1)
        lsum += __shfl_down(lsum, off, 64);
    if ((t & 63) == 0) wred[t >> 6] = lsum;
    __syncthreads();
    if (t == 0) partial[bid] = wred[0] + wred[1] + wred[2] + wred[3];
}

__global__ __launch_bounds__(256) void ssim_finish_kernel(
    const float* __restrict__ partial, float* __restrict__ out)
{
    float s = 0.f;
    for (int i = threadIdx.x; i < NBLK; i += 256) s += partial[i];
    #pragma unroll
    for (int off = 32; off > 0; off >>= 1)
        s += __shfl_down(s, off, 64);
    __shared__ float wred[4];
    if ((threadIdx.x & 63) == 0) wred[threadIdx.x >> 6] = s;
    __syncthreads();
    if (threadIdx.x == 0) {
        float mean = (wred[0] + wred[1] + wred[2] + wred[3]) *
                     (1.0f / (float)(NCH * IMG * IMG));
        out[0] = 1.0f - mean;
    }
}

extern "C" void kernel_launch(void* const* d_in, const int* in_sizes, int n_in,
                              void* d_out, int out_size, void* d_ws, size_t ws_size,
                              hipStream_t stream)
{
    const float* pred = (const float*)d_in[0];
    const float* tgt  = (const float*)d_in[1];
    float* out     = (float*)d_out;
    float* partial = (float*)d_ws;   // NBLK floats = 48 KB, well within ws

    ssim_tile_kernel<<<NBLK, 256, 0, stream>>>(pred, tgt, partial);
    ssim_finish_kernel<<<1, 256, 0, stream>>>(partial, out);
}